// Round 5
// baseline (237.440 us; speedup 1.0000x reference)
//
#include <hip/hip_runtime.h>
#include <hip/hip_bf16.h>
#include <math.h>

#define B_  8
#define C_  64
#define O_  64
#define H_  128
#define W_  128
#define HW_ (H_ * W_)

typedef __attribute__((ext_vector_type(8))) short bf16x8;
typedef __attribute__((ext_vector_type(4))) float f32x4;

__device__ __forceinline__ short f2bf(float f) {
    __hip_bfloat16 h = __float2bfloat16(f);
    return *reinterpret_cast<short*>(&h);
}
__device__ __forceinline__ float bf2f(short u) {
    unsigned int v = ((unsigned int)(unsigned short)u) << 16;
    return __uint_as_float(v);
}

// ---------------------------------------------------------------------------
// Prep 1: bf16 weight layouts for MFMA A-operands (K = kt*64 + c).
//   wbf  [64 o][9 kt][64 c]           (deform)
//   wzbf [32 m][576 k]  rows >=18 = 0 (offset conv, input z)
//   wxbf [16 m][576 k]  rows >= 9 = 0 (mask   conv, input x)
// ---------------------------------------------------------------------------
__global__ void prep_weights(const float* __restrict__ w_off,
                             const float* __restrict__ w_mod,
                             const float* __restrict__ w_reg,
                             short* __restrict__ wbf,
                             short* __restrict__ wzbf,
                             short* __restrict__ wxbf) {
    int t = blockIdx.x * blockDim.x + threadIdx.x;
    if (t < 36864) {
        int o = t / 576, r = t % 576, kt = r / 64, c = r % 64;
        wbf[t] = f2bf(w_reg[o * 576 + c * 9 + kt]);
    }
    if (t < 18432) {
        int m = t / 576, r = t % 576, kt = r / 64, c = r % 64;
        wzbf[t] = (m < 18) ? f2bf(w_off[m * 576 + c * 9 + kt]) : (short)0;
    }
    if (t < 9216) {
        int m = t / 576, r = t % 576, kt = r / 64, c = r % 64;
        wxbf[t] = (m < 9) ? f2bf(w_mod[m * 576 + c * 9 + kt]) : (short)0;
    }
}

// ---------------------------------------------------------------------------
// Prep 2: NCHW fp32 -> NHWC bf16 for x and z (LDS-transposed, coalesced both
// directions).
// ---------------------------------------------------------------------------
__global__ __launch_bounds__(256) void to_nhwc(
    const float* __restrict__ x, const float* __restrict__ z,
    unsigned short* __restrict__ xn, unsigned short* __restrict__ zn) {
    __shared__ float t[64 * 65];
    const int bid = blockIdx.x;
    const int xseg = bid & 1;
    const int y = (bid >> 1) & 127;
    const int b = bid >> 8;

#pragma unroll
    for (int arr = 0; arr < 2; ++arr) {
        const float* src = arr ? z : x;
        unsigned short* dst = arr ? zn : xn;
#pragma unroll
        for (int i = 0; i < 16; ++i) {
            int e = threadIdx.x + i * 256;   // 0..4095
            int c = e >> 6, px = e & 63;
            t[px * 65 + c] =
                src[((size_t)(b * 64 + c) * H_ + y) * W_ + xseg * 64 + px];
        }
        __syncthreads();
#pragma unroll
        for (int i = 0; i < 2; ++i) {
            int j = threadIdx.x + i * 256;   // 0..511
            int px = j >> 3, q = j & 7;
            bf16x8 v;
#pragma unroll
            for (int jj = 0; jj < 8; ++jj)
                v[jj] = f2bf(t[px * 65 + q * 8 + jj]);
            *(bf16x8*)(dst +
                       ((size_t)((b * H_ + y) * W_ + xseg * 64 + px)) * 64 +
                       q * 8) = v;
        }
        __syncthreads();
    }
}

// ---------------------------------------------------------------------------
// Conv via MFMA, LDS-free: each WAVE owns 16 pixels (one row segment).
// Lane = (pixel l15, k-group g). Per step the lane's shifted-window NHWC
// load IS the B-fragment (B[k=g*8+j][col=l15]). 3 MFMA/step, no barriers.
// ---------------------------------------------------------------------------
__global__ __launch_bounds__(256) void conv_mfma3(
    const unsigned short* __restrict__ zn, const unsigned short* __restrict__ xn,
    const short* __restrict__ wzbf, const short* __restrict__ wxbf,
    const float* __restrict__ b_off, const float* __restrict__ b_mod,
    float* __restrict__ off_out,   // [B][18][H][W]
    float* __restrict__ mask_out)  // [B][ 9][H][W]
{
    const int tid = threadIdx.x;
    const int lane = tid & 63;
    const int wv = tid >> 6;
    const int l15 = lane & 15;
    const int g = lane >> 4;

    const int p0 = (blockIdx.x * 4 + wv) * 16;  // wave's first pixel
    const int b = p0 / HW_;
    const int pix0 = p0 % HW_;
    const int ho = pix0 / W_;
    const int wx0 = pix0 % W_;
    const int px = wx0 + l15;  // this lane's pixel x (same row for all 16)

    const unsigned short* znb = zn + (size_t)b * HW_ * 64;
    const unsigned short* xnb = xn + (size_t)b * HW_ * 64;

    f32x4 acc0 = {0.f, 0.f, 0.f, 0.f}, acc1 = acc0, acc2 = acc0;

#pragma unroll 1
    for (int kt = 0; kt < 9; ++kt) {
        const int ky = kt / 3, kx = kt - ky * 3;
        const int iy = ho + ky - 1;
        const int ix = px + kx - 1;
        const bool v = (iy >= 0) && (iy < H_) && (ix >= 0) && (ix < W_);
        const size_t base = ((size_t)(iy * W_ + ix)) * 64;
#pragma unroll
        for (int chalf = 0; chalf < 2; ++chalf) {
            const int step = kt * 2 + chalf;
            const int cb = chalf * 32 + g * 8;
            bf16x8 bz = {0, 0, 0, 0, 0, 0, 0, 0};
            bf16x8 bx = {0, 0, 0, 0, 0, 0, 0, 0};
            if (v) {
                bz = *(const bf16x8*)(znb + base + cb);
                bx = *(const bf16x8*)(xnb + base + cb);
            }
            const int koff = step * 32 + g * 8;
            bf16x8 az0 = *(const bf16x8*)(wzbf + (size_t)l15 * 576 + koff);
            bf16x8 az1 =
                *(const bf16x8*)(wzbf + (size_t)(16 + l15) * 576 + koff);
            bf16x8 ax = *(const bf16x8*)(wxbf + (size_t)l15 * 576 + koff);
            acc0 = __builtin_amdgcn_mfma_f32_16x16x32_bf16(az0, bz, acc0, 0, 0, 0);
            acc1 = __builtin_amdgcn_mfma_f32_16x16x32_bf16(az1, bz, acc1, 0, 0, 0);
            acc2 = __builtin_amdgcn_mfma_f32_16x16x32_bf16(ax, bx, acc2, 0, 0, 0);
        }
    }

    // epilogue: D row = g*4+r, col = l15
    const int pixe = pix0 + l15;
#pragma unroll
    for (int r = 0; r < 4; ++r) {
        const int j0 = g * 4 + r;  // 0..15
        off_out[((size_t)b * 18 + j0) * HW_ + pixe] = acc0[r] + b_off[j0];
        const int j1 = 16 + g * 4 + r;
        if (j1 < 18)
            off_out[((size_t)b * 18 + j1) * HW_ + pixe] = acc1[r] + b_off[j1];
        const int j2 = g * 4 + r;
        if (j2 < 9) {
            float s = acc2[r] + b_mod[j2];
            mask_out[((size_t)b * 9 + j2) * HW_ + pixe] =
                2.f / (1.f + expf(-s));
        }
    }
}

// ---------------------------------------------------------------------------
// Deform via MFMA, LDS-free: wave owns 16 pixels; lane (l15=pixel, g=kgroup)
// samples channels g*8..+7 of its pixel's 4 corners (4x16B contiguous per
// pixel-quad) and the blended bf16x8 IS the B-fragment. 4 MFMA/step.
// ---------------------------------------------------------------------------
__global__ __launch_bounds__(256) void deform_mfma3(
    const unsigned short* __restrict__ xn,
    const float* __restrict__ off_in, const float* __restrict__ mask_in,
    const short* __restrict__ wbf,    // [64 o][9 kt][64 c]
    float* __restrict__ out)
{
    const int tid = threadIdx.x;
    const int lane = tid & 63;
    const int wv = tid >> 6;
    const int l15 = lane & 15;
    const int g = lane >> 4;

    const int p0 = (blockIdx.x * 4 + wv) * 16;
    const int b = p0 / HW_;
    const int pix0 = p0 % HW_;
    const int ho = pix0 / W_;
    const int wx0 = pix0 % W_;
    const int pix = pix0 + l15;

    const unsigned short* xnb = xn + (size_t)b * HW_ * 64;

    f32x4 acc0 = {0.f, 0.f, 0.f, 0.f}, acc1 = acc0, acc2 = acc0, acc3 = acc0;

#pragma unroll 1
    for (int kt = 0; kt < 9; ++kt) {
        // bilinear params for this lane's pixel (g-redundant, cheap)
        float dy = off_in[((size_t)b * 18 + 2 * kt) * HW_ + pix];
        float dx = off_in[((size_t)b * 18 + 2 * kt + 1) * HW_ + pix];
        float m  = mask_in[((size_t)b * 9 + kt) * HW_ + pix];
        float py = dy + (float)(kt / 3 + ho - 1);
        float pxf = dx + (float)(kt % 3 + wx0 + l15 - 1);
        float y0f = floorf(py), x0f = floorf(pxf);
        float wy1 = py - y0f, wy0 = 1.f - wy1;
        float wx1 = pxf - x0f, wx0w = 1.f - wx1;
        int y0 = (int)y0f, x0i = (int)x0f;
        int y1 = y0 + 1, x1 = x0i + 1;
        bool vy0 = (y0 >= 0) && (y0 < H_), vy1 = (y1 >= 0) && (y1 < H_);
        bool vx0 = (x0i >= 0) && (x0i < W_), vx1 = (x1 >= 0) && (x1 < W_);
        float w00 = wy0 * wx0w * ((vy0 && vx0) ? m : 0.f);
        float w01 = wy0 * wx1 * ((vy0 && vx1) ? m : 0.f);
        float w10 = wy1 * wx0w * ((vy1 && vx0) ? m : 0.f);
        float w11 = wy1 * wx1 * ((vy1 && vx1) ? m : 0.f);
        int y0c = min(max(y0, 0), H_ - 1), y1c = min(max(y1, 0), H_ - 1);
        int x0c = min(max(x0i, 0), W_ - 1), x1c = min(max(x1, 0), W_ - 1);
        const size_t a00 = ((size_t)(y0c * W_ + x0c)) * 64;
        const size_t a01 = ((size_t)(y0c * W_ + x1c)) * 64;
        const size_t a10 = ((size_t)(y1c * W_ + x0c)) * 64;
        const size_t a11 = ((size_t)(y1c * W_ + x1c)) * 64;

#pragma unroll
        for (int chalf = 0; chalf < 2; ++chalf) {
            const int step = kt * 2 + chalf;
            const int cb = chalf * 32 + g * 8;
            bf16x8 c00 = *(const bf16x8*)(xnb + a00 + cb);
            bf16x8 c01 = *(const bf16x8*)(xnb + a01 + cb);
            bf16x8 c10 = *(const bf16x8*)(xnb + a10 + cb);
            bf16x8 c11 = *(const bf16x8*)(xnb + a11 + cb);
            bf16x8 sv;
#pragma unroll
            for (int j = 0; j < 8; ++j) {
                float s = bf2f(c00[j]) * w00 + bf2f(c01[j]) * w01 +
                          bf2f(c10[j]) * w10 + bf2f(c11[j]) * w11;
                sv[j] = f2bf(s);
            }
            const int koff = step * 32 + g * 8;
            bf16x8 av0 = *(const bf16x8*)(wbf + (size_t)l15 * 576 + koff);
            bf16x8 av1 =
                *(const bf16x8*)(wbf + (size_t)(16 + l15) * 576 + koff);
            bf16x8 av2 =
                *(const bf16x8*)(wbf + (size_t)(32 + l15) * 576 + koff);
            bf16x8 av3 =
                *(const bf16x8*)(wbf + (size_t)(48 + l15) * 576 + koff);
            acc0 = __builtin_amdgcn_mfma_f32_16x16x32_bf16(av0, sv, acc0, 0, 0, 0);
            acc1 = __builtin_amdgcn_mfma_f32_16x16x32_bf16(av1, sv, acc1, 0, 0, 0);
            acc2 = __builtin_amdgcn_mfma_f32_16x16x32_bf16(av2, sv, acc2, 0, 0, 0);
            acc3 = __builtin_amdgcn_mfma_f32_16x16x32_bf16(av3, sv, acc3, 0, 0, 0);
        }
    }

    // epilogue: o = mf*16 + g*4 + r, pixel = pix0 + l15
#pragma unroll
    for (int mf = 0; mf < 4; ++mf) {
        f32x4 cc = (mf == 0) ? acc0 : ((mf == 1) ? acc1
                    : ((mf == 2) ? acc2 : acc3));
#pragma unroll
        for (int r = 0; r < 4; ++r) {
            const int o = mf * 16 + g * 4 + r;
            out[((size_t)b * O_ + o) * HW_ + pix0 + l15] = cc[r];
        }
    }
}

// ---------------------------------------------------------------------------
// Fallback (no workspace): fully fused fp32, slow but correct.
// ---------------------------------------------------------------------------
__global__ __launch_bounds__(256) void deform_fallback(
    const float* __restrict__ x, const float* __restrict__ z,
    const float* __restrict__ w_regp,
    const float* __restrict__ w_off, const float* __restrict__ b_off,
    const float* __restrict__ w_mod, const float* __restrict__ b_mod,
    float* __restrict__ out) {
    int p = blockIdx.x * blockDim.x + threadIdx.x;
    if (p >= B_ * HW_) return;
    int wo = p % W_;
    int ho = (p / W_) % H_;
    int b  = p / HW_;
    int pix = ho * W_ + wo;

    const float* xb = x + (size_t)b * C_ * HW_;

    float accO[18], accM[9];
#pragma unroll
    for (int j = 0; j < 18; ++j) accO[j] = b_off[j];
#pragma unroll
    for (int j = 0; j < 9; ++j) accM[j] = b_mod[j];
    const float* zb = z + (size_t)b * C_ * HW_;
#pragma unroll 1
    for (int c = 0; c < C_; ++c) {
        const float* zc = zb + c * HW_;
        const float* xc = xb + c * HW_;
#pragma unroll
        for (int ky = 0; ky < 3; ++ky) {
            int iy = ho + ky - 1;
            bool vy = (iy >= 0) && (iy < H_);
#pragma unroll
            for (int kx = 0; kx < 3; ++kx) {
                int ix = wo + kx - 1;
                bool v = vy && (ix >= 0) && (ix < W_);
                int k = ky * 3 + kx;
                float zv = v ? zc[iy * W_ + ix] : 0.f;
                float xv = v ? xc[iy * W_ + ix] : 0.f;
#pragma unroll
                for (int j = 0; j < 18; ++j)
                    accO[j] = fmaf(zv, w_off[j * 576 + c * 9 + k], accO[j]);
#pragma unroll
                for (int j = 0; j < 9; ++j)
                    accM[j] = fmaf(xv, w_mod[j * 576 + c * 9 + k], accM[j]);
            }
        }
    }
    float mv[9];
#pragma unroll
    for (int j = 0; j < 9; ++j) mv[j] = 2.f / (1.f + expf(-accM[j]));

    float acc[64];
#pragma unroll
    for (int o = 0; o < 64; ++o) acc[o] = 0.f;

#pragma unroll 1
    for (int k = 0; k < 9; ++k) {
        float dy = accO[2 * k], dx = accO[2 * k + 1], m = mv[k];
        float py = dy + (float)(k / 3 + ho - 1);
        float px = dx + (float)(k % 3 + wo - 1);
        float y0f = floorf(py), x0f = floorf(px);
        float wy1 = py - y0f, wy0 = 1.f - wy1;
        float wx1 = px - x0f, wx0 = 1.f - wx1;
        int y0 = (int)y0f, x0i = (int)x0f;
        int y1 = y0 + 1, x1 = x0i + 1;
        bool vy0 = (y0 >= 0) && (y0 < H_), vy1 = (y1 >= 0) && (y1 < H_);
        bool vx0 = (x0i >= 0) && (x0i < W_), vx1 = (x1 >= 0) && (x1 < W_);
        float w00 = wy0 * wx0 * ((vy0 && vx0) ? m : 0.f);
        float w01 = wy0 * wx1 * ((vy0 && vx1) ? m : 0.f);
        float w10 = wy1 * wx0 * ((vy1 && vx0) ? m : 0.f);
        float w11 = wy1 * wx1 * ((vy1 && vx1) ? m : 0.f);
        int y0c = min(max(y0, 0), H_ - 1), y1c = min(max(y1, 0), H_ - 1);
        int x0c = min(max(x0i, 0), W_ - 1), x1c = min(max(x1, 0), W_ - 1);
        int i00 = y0c * W_ + x0c, i01 = y0c * W_ + x1c;
        int i10 = y1c * W_ + x0c, i11 = y1c * W_ + x1c;
#pragma unroll 1
        for (int c = 0; c < C_; ++c) {
            const float* xc = xb + c * HW_;
            float val = xc[i00] * w00 + xc[i01] * w01 + xc[i10] * w10 +
                        xc[i11] * w11;
            const float* wr = w_regp + c * 9 + k;
#pragma unroll
            for (int o = 0; o < 64; ++o)
                acc[o] = fmaf(val, wr[o * 576], acc[o]);
        }
    }
    float* ob = out + (size_t)b * O_ * HW_ + pix;
#pragma unroll
    for (int o = 0; o < 64; ++o) ob[o * HW_] = acc[o];
}

// ---------------------------------------------------------------------------
extern "C" void kernel_launch(void* const* d_in, const int* in_sizes, int n_in,
                              void* d_out, int out_size, void* d_ws,
                              size_t ws_size, hipStream_t stream) {
    const float* x     = (const float*)d_in[0];
    const float* z     = (const float*)d_in[1];
    const float* w_off = (const float*)d_in[2];
    const float* b_off = (const float*)d_in[3];
    const float* w_mod = (const float*)d_in[4];
    const float* b_mod = (const float*)d_in[5];
    const float* w_reg = (const float*)d_in[6];
    float* out = (float*)d_out;

    // ws layout (bytes):
    //   wbf  73728 | wzbf 36864 | wxbf 18432      -> 129024
    //   xn   16777216 (NHWC bf16)
    //   zn   16777216
    //   off_buf  9437184 (f32)
    //   mask_buf 4718592 (f32)
    const size_t need = 129024 + 2 * 16777216ull + 9437184 + 4718592;

    const int npix = B_ * HW_;   // 131072
    const int nblk = npix / 64;  // 2048 blocks (4 waves x 16 px)

    if (ws_size >= need) {
        short* wbf  = (short*)d_ws;
        short* wzbf = wbf + 36864;
        short* wxbf = wzbf + 18432;
        unsigned short* xn = (unsigned short*)((char*)d_ws + 129024);
        unsigned short* zn = xn + 8388608;
        float* off_buf  = (float*)((char*)d_ws + 129024 + 2 * 16777216ull);
        float* mask_buf = off_buf + (size_t)B_ * 18 * HW_;

        prep_weights<<<144, 256, 0, stream>>>(w_off, w_mod, w_reg, wbf, wzbf,
                                              wxbf);
        to_nhwc<<<2048, 256, 0, stream>>>(x, z, xn, zn);
        conv_mfma3<<<nblk, 256, 0, stream>>>(zn, xn, wzbf, wxbf, b_off, b_mod,
                                             off_buf, mask_buf);
        deform_mfma3<<<nblk, 256, 0, stream>>>(xn, off_buf, mask_buf, wbf,
                                               out);
    } else {
        deform_fallback<<<(npix + 255) / 256, 256, 0, stream>>>(
            x, z, w_reg, w_off, b_off, w_mod, b_mod, out);
    }
}

// Round 6
// 176.565 us; speedup vs baseline: 1.3448x; 1.3448x over previous
//
#include <hip/hip_runtime.h>
#include <hip/hip_bf16.h>
#include <math.h>

#define B_  8
#define C_  64
#define O_  64
#define H_  128
#define W_  128
#define HW_ (H_ * W_)

typedef __attribute__((ext_vector_type(8))) short bf16x8;
typedef __attribute__((ext_vector_type(4))) float f32x4;

__device__ __forceinline__ short f2bf(float f) {
    __hip_bfloat16 h = __float2bfloat16(f);
    return *reinterpret_cast<short*>(&h);
}
__device__ __forceinline__ float bf2f(short u) {
    unsigned int v = ((unsigned int)(unsigned short)u) << 16;
    return __uint_as_float(v);
}

// ---------------------------------------------------------------------------
// Prep 1: bf16 weights, MFMA-A layout [step][mf][l15][g][8]:
// one lane's frag (16B) at ((step*MF+mf)*16+l15)*32+g*8; a wave's frag load
// spans 1KB contiguous. step = kt*2+chalf, A-row = mf*16+l15,
// k-elem c = chalf*32+g*8+j (= input channel).
//   wb2 [18][4][16][4][8]  (deform, 64 out-ch)           36864 sh
//   wz2 [18][2][16][4][8]  (offset conv, rows>=18 -> 0)  18432 sh
//   wx2 [18][1][16][4][8]  (mask conv,  rows>= 9 -> 0)    9216 sh
// ---------------------------------------------------------------------------
__global__ void prep_weights(const float* __restrict__ w_off,
                             const float* __restrict__ w_mod,
                             const float* __restrict__ w_reg,
                             short* __restrict__ wb2,
                             short* __restrict__ wz2,
                             short* __restrict__ wx2) {
    int t = blockIdx.x * blockDim.x + threadIdx.x;
    if (t < 36864) {
        int step = t / 2048, r = t % 2048;
        int mf = r / 512, r2 = r % 512;
        int l = r2 / 32, r3 = r2 % 32;
        int gg = r3 / 8, j = r3 % 8;
        int kt = step >> 1, ch = step & 1;
        int o = mf * 16 + l, c = ch * 32 + gg * 8 + j;
        wb2[t] = f2bf(w_reg[(o * 64 + c) * 9 + kt]);
    }
    if (t < 18432) {
        int step = t / 1024, r = t % 1024;
        int mf = r / 512, r2 = r % 512;
        int l = r2 / 32, r3 = r2 % 32;
        int gg = r3 / 8, j = r3 % 8;
        int kt = step >> 1, ch = step & 1;
        int m = mf * 16 + l, c = ch * 32 + gg * 8 + j;
        wz2[t] = (m < 18) ? f2bf(w_off[(m * 64 + c) * 9 + kt]) : (short)0;
    }
    if (t < 9216) {
        int step = t / 512, r = t % 512;
        int l = r / 32, r3 = r % 32;
        int gg = r3 / 8, j = r3 % 8;
        int kt = step >> 1, ch = step & 1;
        int c = ch * 32 + gg * 8 + j;
        wx2[t] = (l < 9) ? f2bf(w_mod[(l * 64 + c) * 9 + kt]) : (short)0;
    }
}

// ---------------------------------------------------------------------------
// Prep 2: NCHW fp32 -> NHWC bf16 for x and z.
// ---------------------------------------------------------------------------
__global__ __launch_bounds__(256) void to_nhwc(
    const float* __restrict__ x, const float* __restrict__ z,
    unsigned short* __restrict__ xn, unsigned short* __restrict__ zn) {
    __shared__ float t[64 * 65];
    const int bid = blockIdx.x;
    const int xseg = bid & 1;
    const int y = (bid >> 1) & 127;
    const int b = bid >> 8;

#pragma unroll
    for (int arr = 0; arr < 2; ++arr) {
        const float* src = arr ? z : x;
        unsigned short* dst = arr ? zn : xn;
#pragma unroll
        for (int i = 0; i < 16; ++i) {
            int e = threadIdx.x + i * 256;
            int c = e >> 6, px = e & 63;
            t[px * 65 + c] =
                src[((size_t)(b * 64 + c) * H_ + y) * W_ + xseg * 64 + px];
        }
        __syncthreads();
#pragma unroll
        for (int i = 0; i < 2; ++i) {
            int j = threadIdx.x + i * 256;
            int px = j >> 3, q = j & 7;
            bf16x8 v;
#pragma unroll
            for (int jj = 0; jj < 8; ++jj)
                v[jj] = f2bf(t[px * 65 + q * 8 + jj]);
            *(bf16x8*)(dst +
                       ((size_t)((b * H_ + y) * W_ + xseg * 64 + px)) * 64 +
                       q * 8) = v;
        }
        __syncthreads();
    }
}

// ---------------------------------------------------------------------------
// FUSED conv + deform, one wave per 16 pixels, zero LDS, zero barriers.
// Phase A: 3x3 convs (18 offset ch from z, 9 mask ch from x) via MFMA,
//          results stay in accumulators A0/A1/A2.
// Bridge:  bias + sigmoid in-register; deform taps read off/mask via
//          STATIC __shfl (channel j -> lane (j>>2)*16+l15, reg j&3).
// Phase B: modulated deformable conv via MFMA (4 M-frags = 64 out-ch).
// Both phases fully unrolled -> compiler software-pipelines the gathers.
// ---------------------------------------------------------------------------
__global__ __launch_bounds__(256) void dcn_fused(
    const unsigned short* __restrict__ zn, const unsigned short* __restrict__ xn,
    const short* __restrict__ wb2, const short* __restrict__ wz2,
    const short* __restrict__ wx2,
    const float* __restrict__ b_off, const float* __restrict__ b_mod,
    float* __restrict__ out)
{
    const int tid = threadIdx.x;
    const int lane = tid & 63;
    const int wv = tid >> 6;
    const int l15 = lane & 15;
    const int g = lane >> 4;

    const int p0 = (blockIdx.x * 4 + wv) * 16;
    const int b = p0 / HW_;
    const int pix0 = p0 % HW_;
    const int ho = pix0 / W_;
    const int wx0 = pix0 % W_;
    const int px = wx0 + l15;

    const unsigned short* znb = zn + (size_t)b * HW_ * 64;
    const unsigned short* xnb = xn + (size_t)b * HW_ * 64;

    // ---------------- Phase A: offset/mask convs ----------------
    f32x4 A0 = {0.f, 0.f, 0.f, 0.f}, A1 = A0, A2 = A0;

#pragma unroll
    for (int kt = 0; kt < 9; ++kt) {
        const int iy = ho + kt / 3 - 1;
        const int ix = px + kt % 3 - 1;
        const bool v = (iy >= 0) && (iy < H_) && (ix >= 0) && (ix < W_);
        const size_t base = ((size_t)(iy * W_ + ix)) * 64;
#pragma unroll
        for (int ch = 0; ch < 2; ++ch) {
            const int step = kt * 2 + ch;
            const int cb = ch * 32 + g * 8;
            bf16x8 bz = {0, 0, 0, 0, 0, 0, 0, 0};
            bf16x8 bx = {0, 0, 0, 0, 0, 0, 0, 0};
            if (v) {
                bz = *(const bf16x8*)(znb + base + cb);
                bx = *(const bf16x8*)(xnb + base + cb);
            }
            bf16x8 az0 = *(const bf16x8*)(
                wz2 + (size_t)((step * 2 + 0) * 16 + l15) * 32 + g * 8);
            bf16x8 az1 = *(const bf16x8*)(
                wz2 + (size_t)((step * 2 + 1) * 16 + l15) * 32 + g * 8);
            bf16x8 ax = *(const bf16x8*)(
                wx2 + (size_t)(step * 16 + l15) * 32 + g * 8);
            A0 = __builtin_amdgcn_mfma_f32_16x16x32_bf16(az0, bz, A0, 0, 0, 0);
            A1 = __builtin_amdgcn_mfma_f32_16x16x32_bf16(az1, bz, A1, 0, 0, 0);
            A2 = __builtin_amdgcn_mfma_f32_16x16x32_bf16(ax, bx, A2, 0, 0, 0);
        }
    }

    // ---------------- Bridge: bias + sigmoid, in-register ----------------
    // Lane (g,l15) holds off channels g*4+r (A0), 16+r for g==0 (A1),
    // mask channels g*4+r (A2), all for pixel l15.
#pragma unroll
    for (int r = 0; r < 4; ++r) A0[r] += b_off[g * 4 + r];
    if (g == 0) {
        A1[0] += b_off[16];
        A1[1] += b_off[17];
    }
    float mk[4];
#pragma unroll
    for (int r = 0; r < 4; ++r) {
        int jm = g * 4 + r;
        jm = (jm > 8) ? 8 : jm;  // rows >8 are padding; clamp for safe load
        mk[r] = 2.f / (1.f + expf(-(A2[r] + b_mod[jm])));
    }

    // ---------------- Phase B: deformable conv ----------------
    f32x4 D0 = {0.f, 0.f, 0.f, 0.f}, D1 = D0, D2 = D0, D3 = D0;

#pragma unroll
    for (int kt = 0; kt < 9; ++kt) {
        // static shfl: off ch 2kt, 2kt+1 ; mask ch kt
        float dy, dx;
        if (kt < 8) {
            dy = __shfl(A0[(2 * kt) & 3], ((2 * kt) >> 2) * 16 + l15, 64);
            dx = __shfl(A0[(2 * kt + 1) & 3], ((2 * kt + 1) >> 2) * 16 + l15,
                        64);
        } else {
            dy = __shfl(A1[0], l15, 64);
            dx = __shfl(A1[1], l15, 64);
        }
        float m = __shfl(mk[kt & 3], (kt >> 2) * 16 + l15, 64);

        float py = dy + (float)(kt / 3 + ho - 1);
        float pxf = dx + (float)(kt % 3 + wx0 + l15 - 1);
        float y0f = floorf(py), x0f = floorf(pxf);
        float wy1 = py - y0f, wy0 = 1.f - wy1;
        float wx1 = pxf - x0f, wx0w = 1.f - wx1;
        int y0 = (int)y0f, x0i = (int)x0f;
        int y1 = y0 + 1, x1 = x0i + 1;
        bool vy0 = (y0 >= 0) && (y0 < H_), vy1 = (y1 >= 0) && (y1 < H_);
        bool vx0 = (x0i >= 0) && (x0i < W_), vx1 = (x1 >= 0) && (x1 < W_);
        float w00 = wy0 * wx0w * ((vy0 && vx0) ? m : 0.f);
        float w01 = wy0 * wx1 * ((vy0 && vx1) ? m : 0.f);
        float w10 = wy1 * wx0w * ((vy1 && vx0) ? m : 0.f);
        float w11 = wy1 * wx1 * ((vy1 && vx1) ? m : 0.f);
        int y0c = min(max(y0, 0), H_ - 1), y1c = min(max(y1, 0), H_ - 1);
        int x0c = min(max(x0i, 0), W_ - 1), x1c = min(max(x1, 0), W_ - 1);
        const size_t a00 = ((size_t)(y0c * W_ + x0c)) * 64;
        const size_t a01 = ((size_t)(y0c * W_ + x1c)) * 64;
        const size_t a10 = ((size_t)(y1c * W_ + x0c)) * 64;
        const size_t a11 = ((size_t)(y1c * W_ + x1c)) * 64;

#pragma unroll
        for (int ch = 0; ch < 2; ++ch) {
            const int step = kt * 2 + ch;
            const int cb = ch * 32 + g * 8;
            bf16x8 c00 = *(const bf16x8*)(xnb + a00 + cb);
            bf16x8 c01 = *(const bf16x8*)(xnb + a01 + cb);
            bf16x8 c10 = *(const bf16x8*)(xnb + a10 + cb);
            bf16x8 c11 = *(const bf16x8*)(xnb + a11 + cb);
            bf16x8 sv;
#pragma unroll
            for (int j = 0; j < 8; ++j) {
                float s = bf2f(c00[j]) * w00 + bf2f(c01[j]) * w01 +
                          bf2f(c10[j]) * w10 + bf2f(c11[j]) * w11;
                sv[j] = f2bf(s);
            }
            bf16x8 a0 = *(const bf16x8*)(
                wb2 + (size_t)((step * 4 + 0) * 16 + l15) * 32 + g * 8);
            bf16x8 a1 = *(const bf16x8*)(
                wb2 + (size_t)((step * 4 + 1) * 16 + l15) * 32 + g * 8);
            bf16x8 a2 = *(const bf16x8*)(
                wb2 + (size_t)((step * 4 + 2) * 16 + l15) * 32 + g * 8);
            bf16x8 a3 = *(const bf16x8*)(
                wb2 + (size_t)((step * 4 + 3) * 16 + l15) * 32 + g * 8);
            D0 = __builtin_amdgcn_mfma_f32_16x16x32_bf16(a0, sv, D0, 0, 0, 0);
            D1 = __builtin_amdgcn_mfma_f32_16x16x32_bf16(a1, sv, D1, 0, 0, 0);
            D2 = __builtin_amdgcn_mfma_f32_16x16x32_bf16(a2, sv, D2, 0, 0, 0);
            D3 = __builtin_amdgcn_mfma_f32_16x16x32_bf16(a3, sv, D3, 0, 0, 0);
        }
    }

    // epilogue: o = mf*16 + g*4 + r, pixel = pix0 + l15
#pragma unroll
    for (int mf = 0; mf < 4; ++mf) {
        f32x4 cc = (mf == 0) ? D0 : ((mf == 1) ? D1 : ((mf == 2) ? D2 : D3));
#pragma unroll
        for (int r = 0; r < 4; ++r) {
            const int o = mf * 16 + g * 4 + r;
            out[((size_t)b * O_ + o) * HW_ + pix0 + l15] = cc[r];
        }
    }
}

// ---------------------------------------------------------------------------
// Fallback (no workspace): fully fused fp32, slow but correct.
// ---------------------------------------------------------------------------
__global__ __launch_bounds__(256) void deform_fallback(
    const float* __restrict__ x, const float* __restrict__ z,
    const float* __restrict__ w_regp,
    const float* __restrict__ w_off, const float* __restrict__ b_off,
    const float* __restrict__ w_mod, const float* __restrict__ b_mod,
    float* __restrict__ out) {
    int p = blockIdx.x * blockDim.x + threadIdx.x;
    if (p >= B_ * HW_) return;
    int wo = p % W_;
    int ho = (p / W_) % H_;
    int b  = p / HW_;
    int pix = ho * W_ + wo;

    const float* xb = x + (size_t)b * C_ * HW_;

    float accO[18], accM[9];
#pragma unroll
    for (int j = 0; j < 18; ++j) accO[j] = b_off[j];
#pragma unroll
    for (int j = 0; j < 9; ++j) accM[j] = b_mod[j];
    const float* zb = z + (size_t)b * C_ * HW_;
#pragma unroll 1
    for (int c = 0; c < C_; ++c) {
        const float* zc = zb + c * HW_;
        const float* xc = xb + c * HW_;
#pragma unroll
        for (int ky = 0; ky < 3; ++ky) {
            int iy = ho + ky - 1;
            bool vy = (iy >= 0) && (iy < H_);
#pragma unroll
            for (int kx = 0; kx < 3; ++kx) {
                int ix = wo + kx - 1;
                bool v = vy && (ix >= 0) && (ix < W_);
                int k = ky * 3 + kx;
                float zv = v ? zc[iy * W_ + ix] : 0.f;
                float xv = v ? xc[iy * W_ + ix] : 0.f;
#pragma unroll
                for (int j = 0; j < 18; ++j)
                    accO[j] = fmaf(zv, w_off[j * 576 + c * 9 + k], accO[j]);
#pragma unroll
                for (int j = 0; j < 9; ++j)
                    accM[j] = fmaf(xv, w_mod[j * 576 + c * 9 + k], accM[j]);
            }
        }
    }
    float mv[9];
#pragma unroll
    for (int j = 0; j < 9; ++j) mv[j] = 2.f / (1.f + expf(-accM[j]));

    float acc[64];
#pragma unroll
    for (int o = 0; o < 64; ++o) acc[o] = 0.f;

#pragma unroll 1
    for (int k = 0; k < 9; ++k) {
        float dy = accO[2 * k], dx = accO[2 * k + 1], m = mv[k];
        float py = dy + (float)(k / 3 + ho - 1);
        float px = dx + (float)(k % 3 + wo - 1);
        float y0f = floorf(py), x0f = floorf(px);
        float wy1 = py - y0f, wy0 = 1.f - wy1;
        float wx1 = px - x0f, wx0 = 1.f - wx1;
        int y0 = (int)y0f, x0i = (int)x0f;
        int y1 = y0 + 1, x1 = x0i + 1;
        bool vy0 = (y0 >= 0) && (y0 < H_), vy1 = (y1 >= 0) && (y1 < H_);
        bool vx0 = (x0i >= 0) && (x0i < W_), vx1 = (x1 >= 0) && (x1 < W_);
        float w00 = wy0 * wx0 * ((vy0 && vx0) ? m : 0.f);
        float w01 = wy0 * wx1 * ((vy0 && vx1) ? m : 0.f);
        float w10 = wy1 * wx0 * ((vy1 && vx0) ? m : 0.f);
        float w11 = wy1 * wx1 * ((vy1 && vx1) ? m : 0.f);
        int y0c = min(max(y0, 0), H_ - 1), y1c = min(max(y1, 0), H_ - 1);
        int x0c = min(max(x0i, 0), W_ - 1), x1c = min(max(x1, 0), W_ - 1);
        int i00 = y0c * W_ + x0c, i01 = y0c * W_ + x1c;
        int i10 = y1c * W_ + x0c, i11 = y1c * W_ + x1c;
#pragma unroll 1
        for (int c = 0; c < C_; ++c) {
            const float* xc = xb + c * HW_;
            float val = xc[i00] * w00 + xc[i01] * w01 + xc[i10] * w10 +
                        xc[i11] * w11;
            const float* wr = w_regp + c * 9 + k;
#pragma unroll
            for (int o = 0; o < 64; ++o)
                acc[o] = fmaf(val, wr[o * 576], acc[o]);
        }
    }
    float* ob = out + (size_t)b * O_ * HW_ + pix;
#pragma unroll
    for (int o = 0; o < 64; ++o) ob[o * HW_] = acc[o];
}

// ---------------------------------------------------------------------------
extern "C" void kernel_launch(void* const* d_in, const int* in_sizes, int n_in,
                              void* d_out, int out_size, void* d_ws,
                              size_t ws_size, hipStream_t stream) {
    const float* x     = (const float*)d_in[0];
    const float* z     = (const float*)d_in[1];
    const float* w_off = (const float*)d_in[2];
    const float* b_off = (const float*)d_in[3];
    const float* w_mod = (const float*)d_in[4];
    const float* b_mod = (const float*)d_in[5];
    const float* w_reg = (const float*)d_in[6];
    float* out = (float*)d_out;

    // ws layout (bytes): wb2 73728 | wz2 36864 | wx2 18432  -> 129024
    //                    xn 16777216 | zn 16777216
    const size_t need = 129024 + 2 * 16777216ull;

    const int npix = B_ * HW_;   // 131072
    const int nblk = npix / 64;  // 2048 blocks (4 waves x 16 px)

    if (ws_size >= need) {
        short* wb2 = (short*)d_ws;
        short* wz2 = wb2 + 36864;
        short* wx2 = wz2 + 18432;
        unsigned short* xn = (unsigned short*)((char*)d_ws + 129024);
        unsigned short* zn = xn + 8388608;

        prep_weights<<<144, 256, 0, stream>>>(w_off, w_mod, w_reg, wb2, wz2,
                                              wx2);
        to_nhwc<<<2048, 256, 0, stream>>>(x, z, xn, zn);
        dcn_fused<<<nblk, 256, 0, stream>>>(zn, xn, wb2, wz2, wx2, b_off,
                                            b_mod, out);
    } else {
        deform_fallback<<<(npix + 255) / 256, 256, 0, stream>>>(
            x, z, w_reg, w_off, b_off, w_mod, b_mod, out);
    }
}

// Round 7
// 174.583 us; speedup vs baseline: 1.3600x; 1.0114x over previous
//
#include <hip/hip_runtime.h>
#include <hip/hip_bf16.h>
#include <math.h>

#define B_  8
#define C_  64
#define O_  64
#define H_  128
#define W_  128
#define HW_ (H_ * W_)

typedef __attribute__((ext_vector_type(8))) short bf16x8;
typedef __attribute__((ext_vector_type(4))) float f32x4;

__device__ __forceinline__ short f2bf(float f) {
    __hip_bfloat16 h = __float2bfloat16(f);
    return *reinterpret_cast<short*>(&h);
}
__device__ __forceinline__ float bf2f(short u) {
    unsigned int v = ((unsigned int)(unsigned short)u) << 16;
    return __uint_as_float(v);
}

// ---------------------------------------------------------------------------
// Prep 1: bf16 weights, MFMA-A layout [step][mf][l15][g][8].
//   wb2 [18][4][16][4][8]  (deform)          36864 sh
//   wz2 [18][2][16][4][8]  (offset conv)     18432 sh
//   wx2 [18][1][16][4][8]  (mask conv)        9216 sh
// ---------------------------------------------------------------------------
__global__ void prep_weights(const float* __restrict__ w_off,
                             const float* __restrict__ w_mod,
                             const float* __restrict__ w_reg,
                             short* __restrict__ wb2,
                             short* __restrict__ wz2,
                             short* __restrict__ wx2) {
    int t = blockIdx.x * blockDim.x + threadIdx.x;
    if (t < 36864) {
        int step = t / 2048, r = t % 2048;
        int mf = r / 512, r2 = r % 512;
        int l = r2 / 32, r3 = r2 % 32;
        int gg = r3 / 8, j = r3 % 8;
        int kt = step >> 1, ch = step & 1;
        int o = mf * 16 + l, c = ch * 32 + gg * 8 + j;
        wb2[t] = f2bf(w_reg[(o * 64 + c) * 9 + kt]);
    }
    if (t < 18432) {
        int step = t / 1024, r = t % 1024;
        int mf = r / 512, r2 = r % 512;
        int l = r2 / 32, r3 = r2 % 32;
        int gg = r3 / 8, j = r3 % 8;
        int kt = step >> 1, ch = step & 1;
        int m = mf * 16 + l, c = ch * 32 + gg * 8 + j;
        wz2[t] = (m < 18) ? f2bf(w_off[(m * 64 + c) * 9 + kt]) : (short)0;
    }
    if (t < 9216) {
        int step = t / 512, r = t % 512;
        int l = r / 32, r3 = r % 32;
        int gg = r3 / 8, j = r3 % 8;
        int kt = step >> 1, ch = step & 1;
        int c = ch * 32 + gg * 8 + j;
        wx2[t] = (l < 9) ? f2bf(w_mod[(l * 64 + c) * 9 + kt]) : (short)0;
    }
}

// ---------------------------------------------------------------------------
// Prep 2: NCHW fp32 -> NHWC bf16 for x and z.
// ---------------------------------------------------------------------------
__global__ __launch_bounds__(256) void to_nhwc(
    const float* __restrict__ x, const float* __restrict__ z,
    unsigned short* __restrict__ xn, unsigned short* __restrict__ zn) {
    __shared__ float t[64 * 65];
    const int bid = blockIdx.x;
    const int xseg = bid & 1;
    const int y = (bid >> 1) & 127;
    const int b = bid >> 8;

#pragma unroll
    for (int arr = 0; arr < 2; ++arr) {
        const float* src = arr ? z : x;
        unsigned short* dst = arr ? zn : xn;
#pragma unroll
        for (int i = 0; i < 16; ++i) {
            int e = threadIdx.x + i * 256;
            int c = e >> 6, px = e & 63;
            t[px * 65 + c] =
                src[((size_t)(b * 64 + c) * H_ + y) * W_ + xseg * 64 + px];
        }
        __syncthreads();
#pragma unroll
        for (int i = 0; i < 2; ++i) {
            int j = threadIdx.x + i * 256;
            int px = j >> 3, q = j & 7;
            bf16x8 v;
#pragma unroll
            for (int jj = 0; jj < 8; ++jj)
                v[jj] = f2bf(t[px * 65 + q * 8 + jj]);
            *(bf16x8*)(dst +
                       ((size_t)((b * H_ + y) * W_ + xseg * 64 + px)) * 64 +
                       q * 8) = v;
        }
        __syncthreads();
    }
}

// bilinear tap parameters; offsets are int ELEMENT offsets into NHWC image
__device__ __forceinline__ void tap_params(
    int kt, int ho, int pxi, float dy, float dx, float m,
    float& w00, float& w01, float& w10, float& w11,
    int& a00, int& a01, int& a10, int& a11) {
    float py = dy + (float)(kt / 3 + ho - 1);
    float pxf = dx + (float)(kt % 3 + pxi - 1);
    float y0f = floorf(py), x0f = floorf(pxf);
    float wy1 = py - y0f, wy0 = 1.f - wy1;
    float wx1 = pxf - x0f, wx0w = 1.f - wx1;
    int y0 = (int)y0f, x0i = (int)x0f;
    int y1 = y0 + 1, x1 = x0i + 1;
    bool vy0 = (y0 >= 0) && (y0 < H_), vy1 = (y1 >= 0) && (y1 < H_);
    bool vx0 = (x0i >= 0) && (x0i < W_), vx1 = (x1 >= 0) && (x1 < W_);
    w00 = wy0 * wx0w * ((vy0 && vx0) ? m : 0.f);
    w01 = wy0 * wx1 * ((vy0 && vx1) ? m : 0.f);
    w10 = wy1 * wx0w * ((vy1 && vx0) ? m : 0.f);
    w11 = wy1 * wx1 * ((vy1 && vx1) ? m : 0.f);
    int y0c = min(max(y0, 0), H_ - 1), y1c = min(max(y1, 0), H_ - 1);
    int x0c = min(max(x0i, 0), W_ - 1), x1c = min(max(x1, 0), W_ - 1);
    a00 = (y0c * W_ + x0c) * 64;
    a01 = (y0c * W_ + x1c) * 64;
    a10 = (y1c * W_ + x0c) * 64;
    a11 = (y1c * W_ + x1c) * 64;
}

// ---------------------------------------------------------------------------
// FUSED conv + deform, one wave per 16 pixels, zero LDS, zero barriers,
// explicit 1-deep software pipeline (tap k+1 loads in flight during tap k
// compute) in BOTH phases; XCD swizzle pins each batch image to one XCD L2.
// ---------------------------------------------------------------------------
__global__ __launch_bounds__(256) void dcn_fused(
    const unsigned short* __restrict__ zn, const unsigned short* __restrict__ xn,
    const short* __restrict__ wb2, const short* __restrict__ wz2,
    const short* __restrict__ wx2,
    const float* __restrict__ b_off, const float* __restrict__ b_mod,
    float* __restrict__ out)
{
    const int tid = threadIdx.x;
    const int lane = tid & 63;
    const int wv = tid >> 6;
    const int l15 = lane & 15;
    const int g = lane >> 4;

    // XCD swizzle: 2048 blocks = 8 XCDs x 256; 256 blocks = one image (2MB
    // NHWC, fits one XCD's 4MB L2).
    int bid = (int)blockIdx.x;
    bid = (bid & 7) * 256 + (bid >> 3);

    const int p0 = (bid * 4 + wv) * 16;
    const int b = p0 / HW_;
    const int pix0 = p0 % HW_;
    const int ho = pix0 / W_;
    const int wx0 = pix0 % W_;
    const int px = wx0 + l15;

    const unsigned short* znb = zn + (size_t)b * HW_ * 64;
    const unsigned short* xnb = xn + (size_t)b * HW_ * 64;
    const int g8 = g * 8;

    // ---------------- Phase A: offset/mask convs (pipelined) ----------------
    f32x4 A0 = {0.f, 0.f, 0.f, 0.f}, A1 = A0, A2 = A0;
    const bf16x8 vzero = {0, 0, 0, 0, 0, 0, 0, 0};

    bf16x8 nz0 = vzero, nz1 = vzero, nx0 = vzero, nx1 = vzero;
    {
        const int iy = ho - 1, ix = px - 1;
        if ((iy >= 0) && (ix >= 0) && (ix < W_)) {
            const int base = (iy * W_ + ix) * 64;
            nz0 = *(const bf16x8*)(znb + base + g8);
            nz1 = *(const bf16x8*)(znb + base + 32 + g8);
            nx0 = *(const bf16x8*)(xnb + base + g8);
            nx1 = *(const bf16x8*)(xnb + base + 32 + g8);
        }
    }

#pragma unroll
    for (int kt = 0; kt < 9; ++kt) {
        bf16x8 cz0 = nz0, cz1 = nz1, cx0 = nx0, cx1 = nx1;
        if (kt < 8) {
            const int k2 = kt + 1;
            const int iy = ho + k2 / 3 - 1;
            const int ix = px + k2 % 3 - 1;
            nz0 = vzero; nz1 = vzero; nx0 = vzero; nx1 = vzero;
            if ((iy >= 0) && (iy < H_) && (ix >= 0) && (ix < W_)) {
                const int base = (iy * W_ + ix) * 64;
                nz0 = *(const bf16x8*)(znb + base + g8);
                nz1 = *(const bf16x8*)(znb + base + 32 + g8);
                nx0 = *(const bf16x8*)(xnb + base + g8);
                nx1 = *(const bf16x8*)(xnb + base + 32 + g8);
            }
        }
#pragma unroll
        for (int ch = 0; ch < 2; ++ch) {
            const int step = kt * 2 + ch;
            bf16x8 bz = ch ? cz1 : cz0;
            bf16x8 bx = ch ? cx1 : cx0;
            bf16x8 az0 = *(const bf16x8*)(
                wz2 + (size_t)((step * 2 + 0) * 16 + l15) * 32 + g8);
            bf16x8 az1 = *(const bf16x8*)(
                wz2 + (size_t)((step * 2 + 1) * 16 + l15) * 32 + g8);
            bf16x8 ax = *(const bf16x8*)(
                wx2 + (size_t)(step * 16 + l15) * 32 + g8);
            A0 = __builtin_amdgcn_mfma_f32_16x16x32_bf16(az0, bz, A0, 0, 0, 0);
            A1 = __builtin_amdgcn_mfma_f32_16x16x32_bf16(az1, bz, A1, 0, 0, 0);
            A2 = __builtin_amdgcn_mfma_f32_16x16x32_bf16(ax, bx, A2, 0, 0, 0);
        }
    }

    // ---------------- Bridge: bias + sigmoid, then hoist all shfls ---------
#pragma unroll
    for (int r = 0; r < 4; ++r) A0[r] += b_off[g * 4 + r];
    if (g == 0) {
        A1[0] += b_off[16];
        A1[1] += b_off[17];
    }
    float mk[4];
#pragma unroll
    for (int r = 0; r < 4; ++r) {
        int jm = g * 4 + r;
        jm = (jm > 8) ? 8 : jm;
        mk[r] = 2.f / (1.f + expf(-(A2[r] + b_mod[jm])));
    }

    float dyA[9], dxA[9], mA[9];
#pragma unroll
    for (int kt = 0; kt < 9; ++kt) {
        if (kt < 8) {
            dyA[kt] = __shfl(A0[(2 * kt) & 3], ((2 * kt) >> 2) * 16 + l15, 64);
            dxA[kt] =
                __shfl(A0[(2 * kt + 1) & 3], ((2 * kt + 1) >> 2) * 16 + l15, 64);
        } else {
            dyA[kt] = __shfl(A1[0], l15, 64);
            dxA[kt] = __shfl(A1[1], l15, 64);
        }
        mA[kt] = __shfl(mk[kt & 3], (kt >> 2) * 16 + l15, 64);
    }

    // ---------------- Phase B: deformable conv (pipelined) ----------------
    f32x4 D0 = {0.f, 0.f, 0.f, 0.f}, D1 = D0, D2 = D0, D3 = D0;

    float nw00, nw01, nw10, nw11;
    int na00, na01, na10, na11;
    tap_params(0, ho, wx0 + l15, dyA[0], dxA[0], mA[0], nw00, nw01, nw10,
               nw11, na00, na01, na10, na11);
    bf16x8 n00l = *(const bf16x8*)(xnb + na00 + g8);
    bf16x8 n00h = *(const bf16x8*)(xnb + na00 + 32 + g8);
    bf16x8 n01l = *(const bf16x8*)(xnb + na01 + g8);
    bf16x8 n01h = *(const bf16x8*)(xnb + na01 + 32 + g8);
    bf16x8 n10l = *(const bf16x8*)(xnb + na10 + g8);
    bf16x8 n10h = *(const bf16x8*)(xnb + na10 + 32 + g8);
    bf16x8 n11l = *(const bf16x8*)(xnb + na11 + g8);
    bf16x8 n11h = *(const bf16x8*)(xnb + na11 + 32 + g8);

#pragma unroll
    for (int kt = 0; kt < 9; ++kt) {
        const float w00 = nw00, w01 = nw01, w10 = nw10, w11 = nw11;
        bf16x8 c00l = n00l, c00h = n00h, c01l = n01l, c01h = n01h;
        bf16x8 c10l = n10l, c10h = n10h, c11l = n11l, c11h = n11h;
        if (kt < 8) {
            tap_params(kt + 1, ho, wx0 + l15, dyA[kt + 1], dxA[kt + 1],
                       mA[kt + 1], nw00, nw01, nw10, nw11, na00, na01, na10,
                       na11);
            n00l = *(const bf16x8*)(xnb + na00 + g8);
            n00h = *(const bf16x8*)(xnb + na00 + 32 + g8);
            n01l = *(const bf16x8*)(xnb + na01 + g8);
            n01h = *(const bf16x8*)(xnb + na01 + 32 + g8);
            n10l = *(const bf16x8*)(xnb + na10 + g8);
            n10h = *(const bf16x8*)(xnb + na10 + 32 + g8);
            n11l = *(const bf16x8*)(xnb + na11 + g8);
            n11h = *(const bf16x8*)(xnb + na11 + 32 + g8);
        }
#pragma unroll
        for (int ch = 0; ch < 2; ++ch) {
            const int step = kt * 2 + ch;
            bf16x8 s0 = ch ? c00h : c00l;
            bf16x8 s1 = ch ? c01h : c01l;
            bf16x8 s2 = ch ? c10h : c10l;
            bf16x8 s3 = ch ? c11h : c11l;
            bf16x8 sv;
#pragma unroll
            for (int j = 0; j < 8; ++j) {
                float s = bf2f(s0[j]) * w00 + bf2f(s1[j]) * w01 +
                          bf2f(s2[j]) * w10 + bf2f(s3[j]) * w11;
                sv[j] = f2bf(s);
            }
            bf16x8 a0 = *(const bf16x8*)(
                wb2 + (size_t)((step * 4 + 0) * 16 + l15) * 32 + g8);
            bf16x8 a1 = *(const bf16x8*)(
                wb2 + (size_t)((step * 4 + 1) * 16 + l15) * 32 + g8);
            bf16x8 a2 = *(const bf16x8*)(
                wb2 + (size_t)((step * 4 + 2) * 16 + l15) * 32 + g8);
            bf16x8 a3 = *(const bf16x8*)(
                wb2 + (size_t)((step * 4 + 3) * 16 + l15) * 32 + g8);
            D0 = __builtin_amdgcn_mfma_f32_16x16x32_bf16(a0, sv, D0, 0, 0, 0);
            D1 = __builtin_amdgcn_mfma_f32_16x16x32_bf16(a1, sv, D1, 0, 0, 0);
            D2 = __builtin_amdgcn_mfma_f32_16x16x32_bf16(a2, sv, D2, 0, 0, 0);
            D3 = __builtin_amdgcn_mfma_f32_16x16x32_bf16(a3, sv, D3, 0, 0, 0);
        }
    }

    // epilogue: o = mf*16 + g*4 + r, pixel = pix0 + l15
#pragma unroll
    for (int mf = 0; mf < 4; ++mf) {
        f32x4 cc = (mf == 0) ? D0 : ((mf == 1) ? D1 : ((mf == 2) ? D2 : D3));
#pragma unroll
        for (int r = 0; r < 4; ++r) {
            const int o = mf * 16 + g * 4 + r;
            out[((size_t)b * O_ + o) * HW_ + pix0 + l15] = cc[r];
        }
    }
}

// ---------------------------------------------------------------------------
// Fallback (no workspace): fully fused fp32, slow but correct.
// ---------------------------------------------------------------------------
__global__ __launch_bounds__(256) void deform_fallback(
    const float* __restrict__ x, const float* __restrict__ z,
    const float* __restrict__ w_regp,
    const float* __restrict__ w_off, const float* __restrict__ b_off,
    const float* __restrict__ w_mod, const float* __restrict__ b_mod,
    float* __restrict__ out) {
    int p = blockIdx.x * blockDim.x + threadIdx.x;
    if (p >= B_ * HW_) return;
    int wo = p % W_;
    int ho = (p / W_) % H_;
    int b  = p / HW_;
    int pix = ho * W_ + wo;

    const float* xb = x + (size_t)b * C_ * HW_;

    float accO[18], accM[9];
#pragma unroll
    for (int j = 0; j < 18; ++j) accO[j] = b_off[j];
#pragma unroll
    for (int j = 0; j < 9; ++j) accM[j] = b_mod[j];
    const float* zb = z + (size_t)b * C_ * HW_;
#pragma unroll 1
    for (int c = 0; c < C_; ++c) {
        const float* zc = zb + c * HW_;
        const float* xc = xb + c * HW_;
#pragma unroll
        for (int ky = 0; ky < 3; ++ky) {
            int iy = ho + ky - 1;
            bool vy = (iy >= 0) && (iy < H_);
#pragma unroll
            for (int kx = 0; kx < 3; ++kx) {
                int ix = wo + kx - 1;
                bool v = vy && (ix >= 0) && (ix < W_);
                int k = ky * 3 + kx;
                float zv = v ? zc[iy * W_ + ix] : 0.f;
                float xv = v ? xc[iy * W_ + ix] : 0.f;
#pragma unroll
                for (int j = 0; j < 18; ++j)
                    accO[j] = fmaf(zv, w_off[j * 576 + c * 9 + k], accO[j]);
#pragma unroll
                for (int j = 0; j < 9; ++j)
                    accM[j] = fmaf(xv, w_mod[j * 576 + c * 9 + k], accM[j]);
            }
        }
    }
    float mv[9];
#pragma unroll
    for (int j = 0; j < 9; ++j) mv[j] = 2.f / (1.f + expf(-accM[j]));

    float acc[64];
#pragma unroll
    for (int o = 0; o < 64; ++o) acc[o] = 0.f;

#pragma unroll 1
    for (int k = 0; k < 9; ++k) {
        float dy = accO[2 * k], dx = accO[2 * k + 1], m = mv[k];
        float py = dy + (float)(k / 3 + ho - 1);
        float px = dx + (float)(k % 3 + wo - 1);
        float y0f = floorf(py), x0f = floorf(px);
        float wy1 = py - y0f, wy0 = 1.f - wy1;
        float wx1 = px - x0f, wx0 = 1.f - wx1;
        int y0 = (int)y0f, x0i = (int)x0f;
        int y1 = y0 + 1, x1 = x0i + 1;
        bool vy0 = (y0 >= 0) && (y0 < H_), vy1 = (y1 >= 0) && (y1 < H_);
        bool vx0 = (x0i >= 0) && (x0i < W_), vx1 = (x1 >= 0) && (x1 < W_);
        float w00 = wy0 * wx0 * ((vy0 && vx0) ? m : 0.f);
        float w01 = wy0 * wx1 * ((vy0 && vx1) ? m : 0.f);
        float w10 = wy1 * wx0 * ((vy1 && vx0) ? m : 0.f);
        float w11 = wy1 * wx1 * ((vy1 && vx1) ? m : 0.f);
        int y0c = min(max(y0, 0), H_ - 1), y1c = min(max(y1, 0), H_ - 1);
        int x0c = min(max(x0i, 0), W_ - 1), x1c = min(max(x1, 0), W_ - 1);
        int i00 = y0c * W_ + x0c, i01 = y0c * W_ + x1c;
        int i10 = y1c * W_ + x0c, i11 = y1c * W_ + x1c;
#pragma unroll 1
        for (int c = 0; c < C_; ++c) {
            const float* xc = xb + c * HW_;
            float val = xc[i00] * w00 + xc[i01] * w01 + xc[i10] * w10 +
                        xc[i11] * w11;
            const float* wr = w_regp + c * 9 + k;
#pragma unroll
            for (int o = 0; o < 64; ++o)
                acc[o] = fmaf(val, wr[o * 576], acc[o]);
        }
    }
    float* ob = out + (size_t)b * O_ * HW_ + pix;
#pragma unroll
    for (int o = 0; o < 64; ++o) ob[o * HW_] = acc[o];
}

// ---------------------------------------------------------------------------
extern "C" void kernel_launch(void* const* d_in, const int* in_sizes, int n_in,
                              void* d_out, int out_size, void* d_ws,
                              size_t ws_size, hipStream_t stream) {
    const float* x     = (const float*)d_in[0];
    const float* z     = (const float*)d_in[1];
    const float* w_off = (const float*)d_in[2];
    const float* b_off = (const float*)d_in[3];
    const float* w_mod = (const float*)d_in[4];
    const float* b_mod = (const float*)d_in[5];
    const float* w_reg = (const float*)d_in[6];
    float* out = (float*)d_out;

    // ws layout (bytes): wb2 73728 | wz2 36864 | wx2 18432  -> 129024
    //                    xn 16777216 | zn 16777216
    const size_t need = 129024 + 2 * 16777216ull;

    const int npix = B_ * HW_;   // 131072
    const int nblk = npix / 64;  // 2048 blocks (4 waves x 16 px)

    if (ws_size >= need) {
        short* wb2 = (short*)d_ws;
        short* wz2 = wb2 + 36864;
        short* wx2 = wz2 + 18432;
        unsigned short* xn = (unsigned short*)((char*)d_ws + 129024);
        unsigned short* zn = xn + 8388608;

        prep_weights<<<144, 256, 0, stream>>>(w_off, w_mod, w_reg, wb2, wz2,
                                              wx2);
        to_nhwc<<<2048, 256, 0, stream>>>(x, z, xn, zn);
        dcn_fused<<<nblk, 256, 0, stream>>>(zn, xn, wb2, wz2, wx2, b_off,
                                            b_mod, out);
    } else {
        deform_fallback<<<(npix + 255) / 256, 256, 0, stream>>>(
            x, z, w_reg, w_off, b_off, w_mod, b_mod, out);
    }
}

// Round 8
// 174.252 us; speedup vs baseline: 1.3626x; 1.0019x over previous
//
#include <hip/hip_runtime.h>
#include <hip/hip_bf16.h>
#include <math.h>

#define B_  8
#define C_  64
#define O_  64
#define H_  128
#define W_  128
#define HW_ (H_ * W_)

typedef __attribute__((ext_vector_type(8))) short bf16x8;
typedef __attribute__((ext_vector_type(4))) float f32x4;

__device__ __forceinline__ short f2bf(float f) {
    __hip_bfloat16 h = __float2bfloat16(f);
    return *reinterpret_cast<short*>(&h);
}
__device__ __forceinline__ float bf2f(short u) {
    unsigned int v = ((unsigned int)(unsigned short)u) << 16;
    return __uint_as_float(v);
}

// ---------------------------------------------------------------------------
// Prep 1: bf16 weights, MFMA-A layout [step][mf][l15][g][8].
//   wb2 [18][4][16][4][8]  (deform)          36864 sh
//   wz2 [18][2][16][4][8]  (offset conv)     18432 sh
//   wx2 [18][1][16][4][8]  (mask conv)        9216 sh
// ---------------------------------------------------------------------------
__global__ void prep_weights(const float* __restrict__ w_off,
                             const float* __restrict__ w_mod,
                             const float* __restrict__ w_reg,
                             short* __restrict__ wb2,
                             short* __restrict__ wz2,
                             short* __restrict__ wx2) {
    int t = blockIdx.x * blockDim.x + threadIdx.x;
    if (t < 36864) {
        int step = t / 2048, r = t % 2048;
        int mf = r / 512, r2 = r % 512;
        int l = r2 / 32, r3 = r2 % 32;
        int gg = r3 / 8, j = r3 % 8;
        int kt = step >> 1, ch = step & 1;
        int o = mf * 16 + l, c = ch * 32 + gg * 8 + j;
        wb2[t] = f2bf(w_reg[(o * 64 + c) * 9 + kt]);
    }
    if (t < 18432) {
        int step = t / 1024, r = t % 1024;
        int mf = r / 512, r2 = r % 512;
        int l = r2 / 32, r3 = r2 % 32;
        int gg = r3 / 8, j = r3 % 8;
        int kt = step >> 1, ch = step & 1;
        int m = mf * 16 + l, c = ch * 32 + gg * 8 + j;
        wz2[t] = (m < 18) ? f2bf(w_off[(m * 64 + c) * 9 + kt]) : (short)0;
    }
    if (t < 9216) {
        int step = t / 512, r = t % 512;
        int l = r / 32, r3 = r % 32;
        int gg = r3 / 8, j = r3 % 8;
        int kt = step >> 1, ch = step & 1;
        int c = ch * 32 + gg * 8 + j;
        wx2[t] = (l < 9) ? f2bf(w_mod[(l * 64 + c) * 9 + kt]) : (short)0;
    }
}

// ---------------------------------------------------------------------------
// Prep 2: NCHW fp32 -> NHWC bf16 for x and z.
// ---------------------------------------------------------------------------
__global__ __launch_bounds__(256) void to_nhwc(
    const float* __restrict__ x, const float* __restrict__ z,
    unsigned short* __restrict__ xn, unsigned short* __restrict__ zn) {
    __shared__ float t[64 * 65];
    const int bid = blockIdx.x;
    const int xseg = bid & 1;
    const int y = (bid >> 1) & 127;
    const int b = bid >> 8;

#pragma unroll
    for (int arr = 0; arr < 2; ++arr) {
        const float* src = arr ? z : x;
        unsigned short* dst = arr ? zn : xn;
#pragma unroll
        for (int i = 0; i < 16; ++i) {
            int e = threadIdx.x + i * 256;
            int c = e >> 6, px = e & 63;
            t[px * 65 + c] =
                src[((size_t)(b * 64 + c) * H_ + y) * W_ + xseg * 64 + px];
        }
        __syncthreads();
#pragma unroll
        for (int i = 0; i < 2; ++i) {
            int j = threadIdx.x + i * 256;
            int px = j >> 3, q = j & 7;
            bf16x8 v;
#pragma unroll
            for (int jj = 0; jj < 8; ++jj)
                v[jj] = f2bf(t[px * 65 + q * 8 + jj]);
            *(bf16x8*)(dst +
                       ((size_t)((b * H_ + y) * W_ + xseg * 64 + px)) * 64 +
                       q * 8) = v;
        }
        __syncthreads();
    }
}

// bilinear tap parameters; offsets are int ELEMENT offsets into NHWC image
__device__ __forceinline__ void tap_params(
    int kt, int ho, int pxi, float dy, float dx, float m,
    float& w00, float& w01, float& w10, float& w11,
    int& a00, int& a01, int& a10, int& a11) {
    float py = dy + (float)(kt / 3 + ho - 1);
    float pxf = dx + (float)(kt % 3 + pxi - 1);
    float y0f = floorf(py), x0f = floorf(pxf);
    float wy1 = py - y0f, wy0 = 1.f - wy1;
    float wx1 = pxf - x0f, wx0w = 1.f - wx1;
    int y0 = (int)y0f, x0i = (int)x0f;
    int y1 = y0 + 1, x1 = x0i + 1;
    bool vy0 = (y0 >= 0) && (y0 < H_), vy1 = (y1 >= 0) && (y1 < H_);
    bool vx0 = (x0i >= 0) && (x0i < W_), vx1 = (x1 >= 0) && (x1 < W_);
    w00 = wy0 * wx0w * ((vy0 && vx0) ? m : 0.f);
    w01 = wy0 * wx1 * ((vy0 && vx1) ? m : 0.f);
    w10 = wy1 * wx0w * ((vy1 && vx0) ? m : 0.f);
    w11 = wy1 * wx1 * ((vy1 && vx1) ? m : 0.f);
    int y0c = min(max(y0, 0), H_ - 1), y1c = min(max(y1, 0), H_ - 1);
    int x0c = min(max(x0i, 0), W_ - 1), x1c = min(max(x1, 0), W_ - 1);
    a00 = (y0c * W_ + x0c) * 64;
    a01 = (y0c * W_ + x1c) * 64;
    a10 = (y1c * W_ + x0c) * 64;
    a11 = (y1c * W_ + x1c) * 64;
}

// ---------------------------------------------------------------------------
// FUSED conv + deform, one wave per 16 pixels, zero LDS, zero barriers.
// KEY (R8): per-tap load groups are fenced with sched_barrier(0) so ALL of a
// tap's loads (corners + weight frags) issue back-to-back BEFORE any blend /
// MFMA consumes them -> ~16 outstanding loads per wave instead of 1 (R7 was
// fully serialized: ~470cy per load = one L2 latency each).
// ---------------------------------------------------------------------------
__global__ __launch_bounds__(256) void dcn_fused(
    const unsigned short* __restrict__ zn, const unsigned short* __restrict__ xn,
    const short* __restrict__ wb2, const short* __restrict__ wz2,
    const short* __restrict__ wx2,
    const float* __restrict__ b_off, const float* __restrict__ b_mod,
    float* __restrict__ out)
{
    const int tid = threadIdx.x;
    const int lane = tid & 63;
    const int wv = tid >> 6;
    const int l15 = lane & 15;
    const int g = lane >> 4;

    // XCD swizzle: 2048 blocks = 8 XCDs x 256; one image per XCD L2.
    int bid = (int)blockIdx.x;
    bid = (bid & 7) * 256 + (bid >> 3);

    const int p0 = (bid * 4 + wv) * 16;
    const int b = p0 / HW_;
    const int pix0 = p0 % HW_;
    const int ho = pix0 / W_;
    const int wx0 = pix0 % W_;
    const int px = wx0 + l15;

    const unsigned short* znb = zn + (size_t)b * HW_ * 64;
    const unsigned short* xnb = xn + (size_t)b * HW_ * 64;
    const int g8 = g * 8;

    // ---------------- Phase A: offset/mask convs ----------------
    f32x4 A0 = {0.f, 0.f, 0.f, 0.f}, A1 = A0, A2 = A0;
    const bf16x8 vzero = {0, 0, 0, 0, 0, 0, 0, 0};

#pragma unroll
    for (int kt = 0; kt < 9; ++kt) {
        const int iy = ho + kt / 3 - 1;
        const int ix = px + kt % 3 - 1;
        const bool v = (iy >= 0) && (iy < H_) && (ix >= 0) && (ix < W_);
        const int base = (iy * W_ + ix) * 64;
        const int s0 = kt * 2, s1 = kt * 2 + 1;

        // batch: 4 data loads + 6 weight-frag loads, all independent
        bf16x8 bz0 = vzero, bz1 = vzero, bx0 = vzero, bx1 = vzero;
        if (v) {
            bz0 = *(const bf16x8*)(znb + base + g8);
            bz1 = *(const bf16x8*)(znb + base + 32 + g8);
            bx0 = *(const bf16x8*)(xnb + base + g8);
            bx1 = *(const bf16x8*)(xnb + base + 32 + g8);
        }
        bf16x8 az00 = *(const bf16x8*)(
            wz2 + (size_t)((s0 * 2 + 0) * 16 + l15) * 32 + g8);
        bf16x8 az01 = *(const bf16x8*)(
            wz2 + (size_t)((s0 * 2 + 1) * 16 + l15) * 32 + g8);
        bf16x8 ax0 = *(const bf16x8*)(
            wx2 + (size_t)(s0 * 16 + l15) * 32 + g8);
        bf16x8 az10 = *(const bf16x8*)(
            wz2 + (size_t)((s1 * 2 + 0) * 16 + l15) * 32 + g8);
        bf16x8 az11 = *(const bf16x8*)(
            wz2 + (size_t)((s1 * 2 + 1) * 16 + l15) * 32 + g8);
        bf16x8 ax1 = *(const bf16x8*)(
            wx2 + (size_t)(s1 * 16 + l15) * 32 + g8);
        __builtin_amdgcn_sched_barrier(0);  // fence: loads above, uses below

        A0 = __builtin_amdgcn_mfma_f32_16x16x32_bf16(az00, bz0, A0, 0, 0, 0);
        A1 = __builtin_amdgcn_mfma_f32_16x16x32_bf16(az01, bz0, A1, 0, 0, 0);
        A2 = __builtin_amdgcn_mfma_f32_16x16x32_bf16(ax0, bx0, A2, 0, 0, 0);
        A0 = __builtin_amdgcn_mfma_f32_16x16x32_bf16(az10, bz1, A0, 0, 0, 0);
        A1 = __builtin_amdgcn_mfma_f32_16x16x32_bf16(az11, bz1, A1, 0, 0, 0);
        A2 = __builtin_amdgcn_mfma_f32_16x16x32_bf16(ax1, bx1, A2, 0, 0, 0);
    }

    // ---------------- Bridge: bias + sigmoid, then hoist all shfls ---------
#pragma unroll
    for (int r = 0; r < 4; ++r) A0[r] += b_off[g * 4 + r];
    if (g == 0) {
        A1[0] += b_off[16];
        A1[1] += b_off[17];
    }
    float mk[4];
#pragma unroll
    for (int r = 0; r < 4; ++r) {
        int jm = g * 4 + r;
        jm = (jm > 8) ? 8 : jm;
        mk[r] = 2.f / (1.f + expf(-(A2[r] + b_mod[jm])));
    }

    float dyA[9], dxA[9], mA[9];
#pragma unroll
    for (int kt = 0; kt < 9; ++kt) {
        if (kt < 8) {
            dyA[kt] = __shfl(A0[(2 * kt) & 3], ((2 * kt) >> 2) * 16 + l15, 64);
            dxA[kt] =
                __shfl(A0[(2 * kt + 1) & 3], ((2 * kt + 1) >> 2) * 16 + l15, 64);
        } else {
            dyA[kt] = __shfl(A1[0], l15, 64);
            dxA[kt] = __shfl(A1[1], l15, 64);
        }
        mA[kt] = __shfl(mk[kt & 3], (kt >> 2) * 16 + l15, 64);
    }

    // ---------------- Phase B: deformable conv ----------------
    f32x4 D0 = {0.f, 0.f, 0.f, 0.f}, D1 = D0, D2 = D0, D3 = D0;

#pragma unroll
    for (int kt = 0; kt < 9; ++kt) {
        float w00, w01, w10, w11;
        int a00, a01, a10, a11;
        tap_params(kt, ho, wx0 + l15, dyA[kt], dxA[kt], mA[kt], w00, w01, w10,
                   w11, a00, a01, a10, a11);
        const int s0 = kt * 2, s1 = kt * 2 + 1;

        // batch: 8 corner loads + 8 weight-frag loads, all independent
        bf16x8 c00l = *(const bf16x8*)(xnb + a00 + g8);
        bf16x8 c01l = *(const bf16x8*)(xnb + a01 + g8);
        bf16x8 c10l = *(const bf16x8*)(xnb + a10 + g8);
        bf16x8 c11l = *(const bf16x8*)(xnb + a11 + g8);
        bf16x8 c00h = *(const bf16x8*)(xnb + a00 + 32 + g8);
        bf16x8 c01h = *(const bf16x8*)(xnb + a01 + 32 + g8);
        bf16x8 c10h = *(const bf16x8*)(xnb + a10 + 32 + g8);
        bf16x8 c11h = *(const bf16x8*)(xnb + a11 + 32 + g8);
        bf16x8 a0l = *(const bf16x8*)(
            wb2 + (size_t)((s0 * 4 + 0) * 16 + l15) * 32 + g8);
        bf16x8 a1l = *(const bf16x8*)(
            wb2 + (size_t)((s0 * 4 + 1) * 16 + l15) * 32 + g8);
        bf16x8 a2l = *(const bf16x8*)(
            wb2 + (size_t)((s0 * 4 + 2) * 16 + l15) * 32 + g8);
        bf16x8 a3l = *(const bf16x8*)(
            wb2 + (size_t)((s0 * 4 + 3) * 16 + l15) * 32 + g8);
        bf16x8 a0h = *(const bf16x8*)(
            wb2 + (size_t)((s1 * 4 + 0) * 16 + l15) * 32 + g8);
        bf16x8 a1h = *(const bf16x8*)(
            wb2 + (size_t)((s1 * 4 + 1) * 16 + l15) * 32 + g8);
        bf16x8 a2h = *(const bf16x8*)(
            wb2 + (size_t)((s1 * 4 + 2) * 16 + l15) * 32 + g8);
        bf16x8 a3h = *(const bf16x8*)(
            wb2 + (size_t)((s1 * 4 + 3) * 16 + l15) * 32 + g8);
        __builtin_amdgcn_sched_barrier(0);  // fence: loads above, uses below

        bf16x8 sv0, sv1;
#pragma unroll
        for (int j = 0; j < 8; ++j) {
            float s = fmaf(bf2f(c00l[j]), w00,
                      fmaf(bf2f(c01l[j]), w01,
                      fmaf(bf2f(c10l[j]), w10, bf2f(c11l[j]) * w11)));
            sv0[j] = f2bf(s);
        }
#pragma unroll
        for (int j = 0; j < 8; ++j) {
            float s = fmaf(bf2f(c00h[j]), w00,
                      fmaf(bf2f(c01h[j]), w01,
                      fmaf(bf2f(c10h[j]), w10, bf2f(c11h[j]) * w11)));
            sv1[j] = f2bf(s);
        }
        D0 = __builtin_amdgcn_mfma_f32_16x16x32_bf16(a0l, sv0, D0, 0, 0, 0);
        D1 = __builtin_amdgcn_mfma_f32_16x16x32_bf16(a1l, sv0, D1, 0, 0, 0);
        D2 = __builtin_amdgcn_mfma_f32_16x16x32_bf16(a2l, sv0, D2, 0, 0, 0);
        D3 = __builtin_amdgcn_mfma_f32_16x16x32_bf16(a3l, sv0, D3, 0, 0, 0);
        D0 = __builtin_amdgcn_mfma_f32_16x16x32_bf16(a0h, sv1, D0, 0, 0, 0);
        D1 = __builtin_amdgcn_mfma_f32_16x16x32_bf16(a1h, sv1, D1, 0, 0, 0);
        D2 = __builtin_amdgcn_mfma_f32_16x16x32_bf16(a2h, sv1, D2, 0, 0, 0);
        D3 = __builtin_amdgcn_mfma_f32_16x16x32_bf16(a3h, sv1, D3, 0, 0, 0);
    }

    // epilogue: o = mf*16 + g*4 + r, pixel = pix0 + l15
#pragma unroll
    for (int mf = 0; mf < 4; ++mf) {
        f32x4 cc = (mf == 0) ? D0 : ((mf == 1) ? D1 : ((mf == 2) ? D2 : D3));
#pragma unroll
        for (int r = 0; r < 4; ++r) {
            const int o = mf * 16 + g * 4 + r;
            out[((size_t)b * O_ + o) * HW_ + pix0 + l15] = cc[r];
        }
    }
}

// ---------------------------------------------------------------------------
// Fallback (no workspace): fully fused fp32, slow but correct.
// ---------------------------------------------------------------------------
__global__ __launch_bounds__(256) void deform_fallback(
    const float* __restrict__ x, const float* __restrict__ z,
    const float* __restrict__ w_regp,
    const float* __restrict__ w_off, const float* __restrict__ b_off,
    const float* __restrict__ w_mod, const float* __restrict__ b_mod,
    float* __restrict__ out) {
    int p = blockIdx.x * blockDim.x + threadIdx.x;
    if (p >= B_ * HW_) return;
    int wo = p % W_;
    int ho = (p / W_) % H_;
    int b  = p / HW_;
    int pix = ho * W_ + wo;

    const float* xb = x + (size_t)b * C_ * HW_;

    float accO[18], accM[9];
#pragma unroll
    for (int j = 0; j < 18; ++j) accO[j] = b_off[j];
#pragma unroll
    for (int j = 0; j < 9; ++j) accM[j] = b_mod[j];
    const float* zb = z + (size_t)b * C_ * HW_;
#pragma unroll 1
    for (int c = 0; c < C_; ++c) {
        const float* zc = zb + c * HW_;
        const float* xc = xb + c * HW_;
#pragma unroll
        for (int ky = 0; ky < 3; ++ky) {
            int iy = ho + ky - 1;
            bool vy = (iy >= 0) && (iy < H_);
#pragma unroll
            for (int kx = 0; kx < 3; ++kx) {
                int ix = wo + kx - 1;
                bool v = vy && (ix >= 0) && (ix < W_);
                int k = ky * 3 + kx;
                float zv = v ? zc[iy * W_ + ix] : 0.f;
                float xv = v ? xc[iy * W_ + ix] : 0.f;
#pragma unroll
                for (int j = 0; j < 18; ++j)
                    accO[j] = fmaf(zv, w_off[j * 576 + c * 9 + k], accO[j]);
#pragma unroll
                for (int j = 0; j < 9; ++j)
                    accM[j] = fmaf(xv, w_mod[j * 576 + c * 9 + k], accM[j]);
            }
        }
    }
    float mv[9];
#pragma unroll
    for (int j = 0; j < 9; ++j) mv[j] = 2.f / (1.f + expf(-accM[j]));

    float acc[64];
#pragma unroll
    for (int o = 0; o < 64; ++o) acc[o] = 0.f;

#pragma unroll 1
    for (int k = 0; k < 9; ++k) {
        float dy = accO[2 * k], dx = accO[2 * k + 1], m = mv[k];
        float py = dy + (float)(k / 3 + ho - 1);
        float px = dx + (float)(k % 3 + wo - 1);
        float y0f = floorf(py), x0f = floorf(px);
        float wy1 = py - y0f, wy0 = 1.f - wy1;
        float wx1 = px - x0f, wx0 = 1.f - wx1;
        int y0 = (int)y0f, x0i = (int)x0f;
        int y1 = y0 + 1, x1 = x0i + 1;
        bool vy0 = (y0 >= 0) && (y0 < H_), vy1 = (y1 >= 0) && (y1 < H_);
        bool vx0 = (x0i >= 0) && (x0i < W_), vx1 = (x1 >= 0) && (x1 < W_);
        float w00 = wy0 * wx0 * ((vy0 && vx0) ? m : 0.f);
        float w01 = wy0 * wx1 * ((vy0 && vx1) ? m : 0.f);
        float w10 = wy1 * wx0 * ((vy1 && vx0) ? m : 0.f);
        float w11 = wy1 * wx1 * ((vy1 && vx1) ? m : 0.f);
        int y0c = min(max(y0, 0), H_ - 1), y1c = min(max(y1, 0), H_ - 1);
        int x0c = min(max(x0i, 0), W_ - 1), x1c = min(max(x1, 0), W_ - 1);
        int i00 = y0c * W_ + x0c, i01 = y0c * W_ + x1c;
        int i10 = y1c * W_ + x0c, i11 = y1c * W_ + x1c;
#pragma unroll 1
        for (int c = 0; c < C_; ++c) {
            const float* xc = xb + c * HW_;
            float val = xc[i00] * w00 + xc[i01] * w01 + xc[i10] * w10 +
                        xc[i11] * w11;
            const float* wr = w_regp + c * 9 + k;
#pragma unroll
            for (int o = 0; o < 64; ++o)
                acc[o] = fmaf(val, wr[o * 576], acc[o]);
        }
    }
    float* ob = out + (size_t)b * O_ * HW_ + pix;
#pragma unroll
    for (int o = 0; o < 64; ++o) ob[o * HW_] = acc[o];
}

// ---------------------------------------------------------------------------
extern "C" void kernel_launch(void* const* d_in, const int* in_sizes, int n_in,
                              void* d_out, int out_size, void* d_ws,
                              size_t ws_size, hipStream_t stream) {
    const float* x     = (const float*)d_in[0];
    const float* z     = (const float*)d_in[1];
    const float* w_off = (const float*)d_in[2];
    const float* b_off = (const float*)d_in[3];
    const float* w_mod = (const float*)d_in[4];
    const float* b_mod = (const float*)d_in[5];
    const float* w_reg = (const float*)d_in[6];
    float* out = (float*)d_out;

    // ws layout (bytes): wb2 73728 | wz2 36864 | wx2 18432  -> 129024
    //                    xn 16777216 | zn 16777216
    const size_t need = 129024 + 2 * 16777216ull;

    const int npix = B_ * HW_;   // 131072
    const int nblk = npix / 64;  // 2048 blocks (4 waves x 16 px)

    if (ws_size >= need) {
        short* wb2 = (short*)d_ws;
        short* wz2 = wb2 + 36864;
        short* wx2 = wz2 + 18432;
        unsigned short* xn = (unsigned short*)((char*)d_ws + 129024);
        unsigned short* zn = xn + 8388608;

        prep_weights<<<144, 256, 0, stream>>>(w_off, w_mod, w_reg, wb2, wz2,
                                              wx2);
        to_nhwc<<<2048, 256, 0, stream>>>(x, z, xn, zn);
        dcn_fused<<<nblk, 256, 0, stream>>>(zn, xn, wb2, wz2, wx2, b_off,
                                            b_mod, out);
    } else {
        deform_fallback<<<(npix + 255) / 256, 256, 0, stream>>>(
            x, z, w_reg, w_off, b_off, w_mod, b_mod, out);
    }
}